// Round 20
// baseline (59.923 us; speedup 1.0000x reference)
//
#include <hip/hip_runtime.h>
#include <stdint.h>
#include <stddef.h>

// MultiTaskTrunkNetwork: 3x (Linear+Tanh) [89->64->64->64] + per-task head [64->8]
// Round 20: register-granule experiment. Theory: gfx950 unified VGPR+AGPR file
//   with 64-reg granularity caps every prior config at 4 waves/SIMD (60 VGPR +
//   32 acc > 64 granule). This version halves live acc (two sequential
//   32-feature halves per layer: acc2[2][2]=16 regs), reloads xf per half
//   (L1 hits), defers task/hB to the head -> target TOTAL <= 64 regs ->
//   8 waves/SIMD allocatable. Everything else = r17 (trunk math identical).

typedef _Float16 half8 __attribute__((ext_vector_type(8)));
typedef _Float16 half4 __attribute__((ext_vector_type(4)));
typedef _Float16 half2v __attribute__((ext_vector_type(2)));
typedef float    f32x4 __attribute__((ext_vector_type(4)));

constexpr int BN = 262144, INF = 89, HID = 64, OUTF = 8, NTASK = 50;
constexpr int NTHR = 256;     // 4 waves
constexpr int NW   = 4;       // waves per block
constexpr int ROWS = 128;     // batch rows per block (32 per wave)
constexpr int HP   = 72;      // LDS h pitch in f16 (144 B: 16B-aligned, 2-way banks)

// d_ws layout (bytes) — fragment-ordered weights
constexpr int W0F_OFF = 0;        // [3kk][4ft][64lane][8] f16 = 12288 B
constexpr int W1F_OFF = 12288;    // [2kk][4ft][64lane][8] f16 = 8192 B
constexpr int W2F_OFF = 20480;    // [2kk][4ft][64lane][8] f16 = 8192 B
constexpr int HWT_OFF = 28672;    // [50][8][64] f16 (transposed head weights)

__device__ __forceinline__ float fast_tanh(float v) {
    float e = __expf(2.0f * v);
    return 1.0f - 2.0f * __builtin_amdgcn_rcpf(e + 1.0f);
}

__device__ __forceinline__ float dot2acc(half2v a, half2v b, float c) {
#if __has_builtin(__builtin_amdgcn_fdot2)
    return __builtin_amdgcn_fdot2(a, b, c, false);
#else
    return fmaf((float)a[0], (float)b[0], fmaf((float)a[1], (float)b[1], c));
#endif
}

__global__ void prep_kernel(const float* __restrict__ W0, const float* __restrict__ W1,
                            const float* __restrict__ W2, const float* __restrict__ hW,
                            _Float16* __restrict__ ws) {
    const int tid = blockIdx.x * blockDim.x + threadIdx.x;
    const int stride = gridDim.x * blockDim.x;
    _Float16* w0f = ws + W0F_OFF / 2;
    _Float16* w1f = ws + W1F_OFF / 2;
    _Float16* w2f = ws + W2F_OFF / 2;
    _Float16* hwt = ws + HWT_OFF / 2;
    // layer 0: frag (kk,g) covers k0 = kk*32+g*8, EXCEPT (2,3) which covers
    // k=81..88 with j<7 weights zeroed (those k are duplicated in frag (2,2)).
    for (int i = tid; i < 3 * 4 * 64 * 8; i += stride) {
        int j = i & 7, l = (i >> 3) & 63, fk = i >> 9;   // fk = kk*4+ft
        int kk = fk >> 2, ft = fk & 3;
        int n = ft * 16 + (l & 15);
        int g = l >> 4;
        bool tail = (kk == 2 && g == 3);
        int k = (tail ? 81 : kk * 32 + g * 8) + j;       // always <= 88
        float wv = W0[k * HID + n];
        if (tail && j < 7) wv = 0.0f;                    // duplicate k: zero weight
        w0f[i] = (_Float16)wv;
    }
    for (int i = tid; i < 2 * 4 * 64 * 8; i += stride) {
        int j = i & 7, l = (i >> 3) & 63, fk = i >> 9;
        int kk = fk >> 2, ft = fk & 3;
        int n = ft * 16 + (l & 15);
        int k = kk * 32 + (l >> 4) * 8 + j;
        w1f[i] = (_Float16)W1[k * HID + n];
        w2f[i] = (_Float16)W2[k * HID + n];
    }
    for (int i = tid; i < NTASK * OUTF * HID; i += stride) {   // hwT[t][o][k]
        int t = i / (OUTF * HID), rem = i % (OUTF * HID);
        int o = rem / HID, k = rem % HID;
        hwt[i] = (_Float16)hW[(size_t)t * (HID * OUTF) + k * OUTF + o];
    }
}

__global__ __launch_bounds__(NTHR, 4) void mtn_mfma_kernel(
    const float* __restrict__ x,     // [B, 89]
    const int*   __restrict__ task,  // [B]
    const float* __restrict__ b0, const float* __restrict__ b1,
    const float* __restrict__ b2,
    const float* __restrict__ hB,    // [50, 8] fp32
    const _Float16* __restrict__ ws,
    float* __restrict__ out)         // [B, 8]
{
    __shared__ __align__(16) _Float16 hs[NW][32][HP];   // 18432 B, wave-private bands

    const int t = threadIdx.x;
    const int w = t >> 6;            // wave 0..3
    const int l = t & 63;
    const int c = l & 15;            // MFMA col (batch) / A row (feat)
    const int g = l >> 4;            // k-group / D row-group
    const int waveRow = blockIdx.x * ROWS + w * 32;   // global row base of this wave

    const _Float16* w0f = ws + W0F_OFF / 2;
    const _Float16* w1f = ws + W1F_OFF / 2;
    const _Float16* w2f = ws + W2F_OFF / 2;
    const _Float16* hwt = ws + HWT_OFF / 2;

    const int k0_2 = (g == 3) ? 81 : 64 + g * 8;     // kk==2 chunk start

    // ================= layer 0: two sequential 32-feature halves ==============
    // live per half: acc2 16 + xf 8 + af 4 + addr ~16 -> total <= ~52 regs
    #pragma unroll
    for (int ph = 0; ph < 2; ++ph) {
        f32x4 acc2[2][2];
        #pragma unroll
        for (int f2 = 0; f2 < 2; ++f2) {
            f32x4 bv = *(const f32x4*)(b0 + (ph * 2 + f2) * 16 + g * 4);
            acc2[f2][0] = bv; acc2[f2][1] = bv;
        }
        #pragma unroll
        for (int kk = 0; kk < 3; ++kk) {
            const int k0 = (kk == 2) ? k0_2 : kk * 32 + g * 8;
            half8 xf[2];                       // reloaded per (ph,kk): L1 hits
            #pragma unroll
            for (int bt = 0; bt < 2; ++bt) {
                const float* xr = x + (size_t)(waveRow + bt * 16 + c) * INF;
                float v[8];
                __builtin_memcpy(v, xr + k0, 32);   // in-bounds: k0+8 <= 89
                half8 hb;
                #pragma unroll
                for (int i2 = 0; i2 < 8; ++i2) hb[i2] = (_Float16)v[i2];
                xf[bt] = hb;
            }
            #pragma unroll
            for (int f2 = 0; f2 < 2; ++f2) {
                half8 af = *(const half8*)(w0f + ((kk * 4 + ph * 2 + f2) * 64 + l) * 8);
                acc2[f2][0] = __builtin_amdgcn_mfma_f32_16x16x32_f16(af, xf[0], acc2[f2][0], 0, 0, 0);
                acc2[f2][1] = __builtin_amdgcn_mfma_f32_16x16x32_f16(af, xf[1], acc2[f2][1], 0, 0, 0);
            }
        }
        #pragma unroll
        for (int f2 = 0; f2 < 2; ++f2)
            #pragma unroll
            for (int bt = 0; bt < 2; ++bt) {
                half4 hv;
                #pragma unroll
                for (int r = 0; r < 4; ++r) hv[r] = (_Float16)fast_tanh(acc2[f2][bt][r]);
                *(half4*)&hs[w][bt * 16 + c][(ph * 2 + f2) * 16 + g * 4] = hv;
            }
    }

    // ================= layers 1,2: K=64, same two-half structure ==============
    #pragma unroll
    for (int layer = 0; layer < 2; ++layer) {
        const _Float16* WF  = layer ? w2f : w1f;
        const float*    bia = layer ? b2  : b1;
        // NOTE: both halves of the PREVIOUS layer are complete (sequential phases
        // within the same wave), so reading K=64 from hs is safe.
        f32x4 res2[2][2][2];   // hold both halves' results, write after both read
        #pragma unroll
        for (int ph = 0; ph < 2; ++ph) {
            f32x4 acc2[2][2];
            #pragma unroll
            for (int f2 = 0; f2 < 2; ++f2) {
                f32x4 bv = *(const f32x4*)(bia + (ph * 2 + f2) * 16 + g * 4);
                acc2[f2][0] = bv; acc2[f2][1] = bv;
            }
            #pragma unroll
            for (int kk = 0; kk < 2; ++kk) {
                half8 bf[2];
                #pragma unroll
                for (int bt = 0; bt < 2; ++bt)
                    bf[bt] = *(const half8*)&hs[w][bt * 16 + c][kk * 32 + g * 8];
                #pragma unroll
                for (int f2 = 0; f2 < 2; ++f2) {
                    half8 af = *(const half8*)(WF + ((kk * 4 + ph * 2 + f2) * 64 + l) * 8);
                    acc2[f2][0] = __builtin_amdgcn_mfma_f32_16x16x32_f16(af, bf[0], acc2[f2][0], 0, 0, 0);
                    acc2[f2][1] = __builtin_amdgcn_mfma_f32_16x16x32_f16(af, bf[1], acc2[f2][1], 0, 0, 0);
                }
            }
            #pragma unroll
            for (int f2 = 0; f2 < 2; ++f2)
                #pragma unroll
                for (int bt = 0; bt < 2; ++bt)
                    res2[ph][f2][bt] = acc2[f2][bt];
        }
        // all reads of hs done; now overwrite with this layer's h
        #pragma unroll
        for (int ph = 0; ph < 2; ++ph)
            #pragma unroll
            for (int f2 = 0; f2 < 2; ++f2)
                #pragma unroll
                for (int bt = 0; bt < 2; ++bt) {
                    half4 hv;
                    #pragma unroll
                    for (int r = 0; r < 4; ++r)
                        hv[r] = (_Float16)fast_tanh(res2[ph][f2][bt][r]);
                    *(half4*)&hs[w][bt * 16 + c][(ph * 2 + f2) * 16 + g * 4] = hv;
                }
    }

    // ================= head: loads deferred here (smaller trunk live-set) =========
    const int jr = l >> 3, jo = l & 7;
    #pragma unroll
    for (int it = 0; it < 4; ++it) {
        const int r = it * 8 + jr;
        const size_t grow = (size_t)waveRow + r;
        const int tk = task[grow];
        const float hb = hB[tk * OUTF + jo];
        const _Float16* wp = hwt + (size_t)tk * (OUTF * HID) + jo * 8;  // chunk jo
        const half8 hv = *(const half8*)&hs[w][r][jo * 8];              // 1 read/it

        float p[8];
        #pragma unroll
        for (int o = 0; o < 8; ++o) {
            half8 wv = *(const half8*)(wp + o * HID);   // 8 lanes -> 128B contiguous
            float a = 0.0f;
            #pragma unroll
            for (int pp = 0; pp < 4; ++pp) {
                half2v av = {hv[2 * pp], hv[2 * pp + 1]};
                half2v bv = {wv[2 * pp], wv[2 * pp + 1]};
                a = dot2acc(av, bv, a);
            }
            p[o] = a;
        }
        // transpose-reduce across the 8 jo-lanes (static indices only)
        float t0 = p[0] + __shfl_xor(p[0], 1);
        float t1 = p[1] + __shfl_xor(p[1], 1);
        float t2 = p[2] + __shfl_xor(p[2], 1);
        float t3 = p[3] + __shfl_xor(p[3], 1);
        float t4 = p[4] + __shfl_xor(p[4], 1);
        float t5 = p[5] + __shfl_xor(p[5], 1);
        float t6 = p[6] + __shfl_xor(p[6], 1);
        float t7 = p[7] + __shfl_xor(p[7], 1);
        const bool b0s = (jo & 1) != 0;
        float s0 = b0s ? t1 : t0;
        float s1 = b0s ? t3 : t2;
        float s2 = b0s ? t5 : t4;
        float s3 = b0s ? t7 : t6;
        s0 += __shfl_xor(s0, 2);
        s1 += __shfl_xor(s1, 2);
        s2 += __shfl_xor(s2, 2);
        s3 += __shfl_xor(s3, 2);
        const bool b1s = (jo & 2) != 0;
        float u0 = b1s ? s1 : s0;
        float u1 = b1s ? s3 : s2;
        u0 += __shfl_xor(u0, 4);
        u1 += __shfl_xor(u1, 4);
        float res = ((jo & 4) ? u1 : u0) + hb;
        out[grow * OUTF + jo] = res;    // wave stores 64 consecutive dwords
    }
}

extern "C" void kernel_launch(void* const* d_in, const int* in_sizes, int n_in,
                              void* d_out, int out_size, void* d_ws, size_t ws_size,
                              hipStream_t stream) {
    const float* x    = (const float*)d_in[0];
    const int*   task = (const int*)  d_in[1];
    const float* W0   = (const float*)d_in[2];
    const float* b0   = (const float*)d_in[3];
    const float* W1   = (const float*)d_in[4];
    const float* b1   = (const float*)d_in[5];
    const float* W2   = (const float*)d_in[6];
    const float* b2   = (const float*)d_in[7];
    const float* hW   = (const float*)d_in[8];
    const float* hB   = (const float*)d_in[9];
    float* out = (float*)d_out;
    _Float16* ws = (_Float16*)d_ws;

    prep_kernel<<<64, 256, 0, stream>>>(W0, W1, W2, hW, ws);
    mtn_mfma_kernel<<<BN / ROWS, NTHR, 0, stream>>>(x, task, b0, b1, b2, hB, ws, out);
}

// Round 21
// 39.965 us; speedup vs baseline: 1.4994x; 1.4994x over previous
//
#include <hip/hip_runtime.h>
#include <stdint.h>
#include <stddef.h>

// MultiTaskTrunkNetwork: 3x (Linear+Tanh) [89->64->64->64] + per-task head [64->8]
// Round 21: weights -> LDS (L1-request-throughput theory).
//   Only two changes ever helped (r6, r8) and both cut cache-lines/instr.
//   Remaining movable L1 stream: 28KB of frag-ordered weights re-read by EVERY
//   wave (~450 lines/wave). Stage them once per block into LDS (7 coalesced
//   float4/thread + 1 barrier); af loads become ds_read_b128 on the idle LDS
//   pipe. x stays direct-global (r14), head unchanged (already minimal).
//   Base: r17 (4-wave, 256thr, bounds(256,4)). LDS 47.1KB -> 3 blocks/CU.

typedef _Float16 half8 __attribute__((ext_vector_type(8)));
typedef _Float16 half4 __attribute__((ext_vector_type(4)));
typedef _Float16 half2v __attribute__((ext_vector_type(2)));
typedef float    f32x4 __attribute__((ext_vector_type(4)));

constexpr int BN = 262144, INF = 89, HID = 64, OUTF = 8, NTASK = 50;
constexpr int NTHR = 256;     // 4 waves
constexpr int NW   = 4;       // waves per block
constexpr int ROWS = 128;     // batch rows per block (32 per wave)
constexpr int HP   = 72;      // LDS h pitch in f16 (144 B: 16B-aligned, 2-way banks)
constexpr int WLF  = 14336;   // frag-ordered weights in f16 (28672 B, contiguous)

// d_ws layout (bytes) — fragment-ordered weights (contiguous block of 28672 B)
constexpr int W0F_OFF = 0;        // [3kk][4ft][64lane][8] f16 = 12288 B
constexpr int W1F_OFF = 12288;    // [2kk][4ft][64lane][8] f16 = 8192 B
constexpr int W2F_OFF = 20480;    // [2kk][4ft][64lane][8] f16 = 8192 B
constexpr int HWT_OFF = 28672;    // [50][8][64] f16 (transposed head weights)

__device__ __forceinline__ float fast_tanh(float v) {
    float e = __expf(2.0f * v);
    return 1.0f - 2.0f * __builtin_amdgcn_rcpf(e + 1.0f);
}

__device__ __forceinline__ float dot2acc(half2v a, half2v b, float c) {
#if __has_builtin(__builtin_amdgcn_fdot2)
    return __builtin_amdgcn_fdot2(a, b, c, false);
#else
    return fmaf((float)a[0], (float)b[0], fmaf((float)a[1], (float)b[1], c));
#endif
}

__global__ void prep_kernel(const float* __restrict__ W0, const float* __restrict__ W1,
                            const float* __restrict__ W2, const float* __restrict__ hW,
                            _Float16* __restrict__ ws) {
    const int tid = blockIdx.x * blockDim.x + threadIdx.x;
    const int stride = gridDim.x * blockDim.x;
    _Float16* w0f = ws + W0F_OFF / 2;
    _Float16* w1f = ws + W1F_OFF / 2;
    _Float16* w2f = ws + W2F_OFF / 2;
    _Float16* hwt = ws + HWT_OFF / 2;
    // layer 0: frag (kk,g) covers k0 = kk*32+g*8, EXCEPT (2,3) which covers
    // k=81..88 with j<7 weights zeroed (those k are duplicated in frag (2,2)).
    for (int i = tid; i < 3 * 4 * 64 * 8; i += stride) {
        int j = i & 7, l = (i >> 3) & 63, fk = i >> 9;   // fk = kk*4+ft
        int kk = fk >> 2, ft = fk & 3;
        int n = ft * 16 + (l & 15);
        int g = l >> 4;
        bool tail = (kk == 2 && g == 3);
        int k = (tail ? 81 : kk * 32 + g * 8) + j;       // always <= 88
        float wv = W0[k * HID + n];
        if (tail && j < 7) wv = 0.0f;                    // duplicate k: zero weight
        w0f[i] = (_Float16)wv;
    }
    for (int i = tid; i < 2 * 4 * 64 * 8; i += stride) {
        int j = i & 7, l = (i >> 3) & 63, fk = i >> 9;
        int kk = fk >> 2, ft = fk & 3;
        int n = ft * 16 + (l & 15);
        int k = kk * 32 + (l >> 4) * 8 + j;
        w1f[i] = (_Float16)W1[k * HID + n];
        w2f[i] = (_Float16)W2[k * HID + n];
    }
    for (int i = tid; i < NTASK * OUTF * HID; i += stride) {   // hwT[t][o][k]
        int t = i / (OUTF * HID), rem = i % (OUTF * HID);
        int o = rem / HID, k = rem % HID;
        hwt[i] = (_Float16)hW[(size_t)t * (HID * OUTF) + k * OUTF + o];
    }
}

__global__ __launch_bounds__(NTHR, 4) void mtn_mfma_kernel(
    const float* __restrict__ x,     // [B, 89]
    const int*   __restrict__ task,  // [B]
    const float* __restrict__ b0, const float* __restrict__ b1,
    const float* __restrict__ b2,
    const float* __restrict__ hB,    // [50, 8] fp32
    const _Float16* __restrict__ ws,
    float* __restrict__ out)         // [B, 8]
{
    __shared__ __align__(16) _Float16 wl[WLF];          // 28672 B: W0F|W1F|W2F
    __shared__ __align__(16) _Float16 hs[NW][32][HP];   // 18432 B, wave-private bands

    const int t = threadIdx.x;
    const int w = t >> 6;            // wave 0..3
    const int l = t & 63;
    const int c = l & 15;            // MFMA col (batch) / A row (feat)
    const int g = l >> 4;            // k-group / D row-group
    const int waveRow = blockIdx.x * ROWS + w * 32;   // global row base of this wave

    const _Float16* hwt = ws + HWT_OFF / 2;

    // ---- stage ALL trunk weights to LDS: 1792 float4 = 7 per thread, coalesced
    {
        const float4* src = reinterpret_cast<const float4*>(ws);   // frag block @0
        float4* dst = reinterpret_cast<float4*>(wl);
        #pragma unroll
        for (int i = 0; i < 7; ++i) dst[t + i * NTHR] = src[t + i * NTHR];
    }

    // ---- layer-0 B-fragments: direct global->VGPR, branchless (overlapped tail)
    // (issued before the barrier so HBM latency overlaps the weight staging)
    const int k0_2 = (g == 3) ? 81 : 64 + g * 8;     // kk==2 chunk start
    half8 xf[3][2];
    #pragma unroll
    for (int bt = 0; bt < 2; ++bt) {
        const float* xr = x + (size_t)(waveRow + bt * 16 + c) * INF;
        #pragma unroll
        for (int kk = 0; kk < 3; ++kk) {
            const int k0 = (kk == 2) ? k0_2 : kk * 32 + g * 8;
            float v[8];
            __builtin_memcpy(v, xr + k0, 32);        // in-bounds: k0+8 <= 89
            half8 hb;
            #pragma unroll
            for (int i2 = 0; i2 < 8; ++i2) hb[i2] = (_Float16)v[i2];
            xf[kk][bt] = hb;
        }
    }

    // ---- task indices + head biases
    const int jr = l >> 3, jo = l & 7;
    int   tks[4];
    float hBv[4];
    #pragma unroll
    for (int it = 0; it < 4; ++it)
        tks[it] = task[waveRow + it * 8 + jr];
    #pragma unroll
    for (int it = 0; it < 4; ++it)
        hBv[it] = hB[tks[it] * OUTF + jo];

    __syncthreads();   // weights staged; all af reads below hit LDS

    const _Float16* w0l = wl;                 // [3kk][4ft][64][8]
    const _Float16* w1l = wl + W1F_OFF / 2;   // [2kk][4ft][64][8]
    const _Float16* w2l = wl + W2F_OFF / 2;

    f32x4 acc[4][2];   // [feat-tile][batch-tile]

    // ================= layer 0: K=96-equivalent, A frags from LDS =================
    #pragma unroll
    for (int ft = 0; ft < 4; ++ft) {
        f32x4 bv = *(const f32x4*)(b0 + ft * 16 + g * 4);
        acc[ft][0] = bv; acc[ft][1] = bv;
    }
    #pragma unroll
    for (int kk = 0; kk < 3; ++kk)
        #pragma unroll
        for (int ft = 0; ft < 4; ++ft) {
            half8 af = *(const half8*)(w0l + ((kk * 4 + ft) * 64 + l) * 8);  // ds_read_b128
            acc[ft][0] = __builtin_amdgcn_mfma_f32_16x16x32_f16(af, xf[kk][0], acc[ft][0], 0, 0, 0);
            acc[ft][1] = __builtin_amdgcn_mfma_f32_16x16x32_f16(af, xf[kk][1], acc[ft][1], 0, 0, 0);
        }
    #pragma unroll
    for (int ft = 0; ft < 4; ++ft)
        #pragma unroll
        for (int bt = 0; bt < 2; ++bt) {
            half4 hv;
            #pragma unroll
            for (int r = 0; r < 4; ++r) hv[r] = (_Float16)fast_tanh(acc[ft][bt][r]);
            *(half4*)&hs[w][bt * 16 + c][ft * 16 + g * 4] = hv;   // 8B store
        }

    // ================= layers 1,2: K=64, A and B both from LDS =============
    #pragma unroll
    for (int layer = 0; layer < 2; ++layer) {
        const _Float16* WL  = layer ? w2l : w1l;
        const float*    bia = layer ? b2  : b1;
        #pragma unroll
        for (int ft = 0; ft < 4; ++ft) {
            f32x4 bv = *(const f32x4*)(bia + ft * 16 + g * 4);
            acc[ft][0] = bv; acc[ft][1] = bv;
        }
        #pragma unroll
        for (int kk = 0; kk < 2; ++kk) {
            half8 bf[2];
            #pragma unroll
            for (int bt = 0; bt < 2; ++bt)
                bf[bt] = *(const half8*)&hs[w][bt * 16 + c][kk * 32 + g * 8];  // 16B read
            #pragma unroll
            for (int ft = 0; ft < 4; ++ft) {
                half8 af = *(const half8*)(WL + ((kk * 4 + ft) * 64 + l) * 8);
                acc[ft][0] = __builtin_amdgcn_mfma_f32_16x16x32_f16(af, bf[0], acc[ft][0], 0, 0, 0);
                acc[ft][1] = __builtin_amdgcn_mfma_f32_16x16x32_f16(af, bf[1], acc[ft][1], 0, 0, 0);
            }
        }
        #pragma unroll
        for (int ft = 0; ft < 4; ++ft)
            #pragma unroll
            for (int bt = 0; bt < 2; ++bt) {
                half4 hv;
                #pragma unroll
                for (int r = 0; r < 4; ++r) hv[r] = (_Float16)fast_tanh(acc[ft][bt][r]);
                *(half4*)&hs[w][bt * 16 + c][ft * 16 + g * 4] = hv;
            }
    }

    // ================= head: coalesced weight chunks + transpose-reduce =============
    #pragma unroll
    for (int it = 0; it < 4; ++it) {
        const int r = it * 8 + jr;
        const size_t grow = (size_t)waveRow + r;
        const int tk = tks[it];
        const _Float16* wp = hwt + (size_t)tk * (OUTF * HID) + jo * 8;  // chunk jo
        const half8 hv = *(const half8*)&hs[w][r][jo * 8];              // 1 read/it

        float p[8];
        #pragma unroll
        for (int o = 0; o < 8; ++o) {
            half8 wv = *(const half8*)(wp + o * HID);   // 8 lanes -> 128B contiguous
            float a = 0.0f;
            #pragma unroll
            for (int pp = 0; pp < 4; ++pp) {
                half2v av = {hv[2 * pp], hv[2 * pp + 1]};
                half2v bv = {wv[2 * pp], wv[2 * pp + 1]};
                a = dot2acc(av, bv, a);
            }
            p[o] = a;
        }
        // transpose-reduce across the 8 jo-lanes (static indices only)
        float t0 = p[0] + __shfl_xor(p[0], 1);
        float t1 = p[1] + __shfl_xor(p[1], 1);
        float t2 = p[2] + __shfl_xor(p[2], 1);
        float t3 = p[3] + __shfl_xor(p[3], 1);
        float t4 = p[4] + __shfl_xor(p[4], 1);
        float t5 = p[5] + __shfl_xor(p[5], 1);
        float t6 = p[6] + __shfl_xor(p[6], 1);
        float t7 = p[7] + __shfl_xor(p[7], 1);
        const bool b0s = (jo & 1) != 0;
        float s0 = b0s ? t1 : t0;
        float s1 = b0s ? t3 : t2;
        float s2 = b0s ? t5 : t4;
        float s3 = b0s ? t7 : t6;
        s0 += __shfl_xor(s0, 2);
        s1 += __shfl_xor(s1, 2);
        s2 += __shfl_xor(s2, 2);
        s3 += __shfl_xor(s3, 2);
        const bool b1s = (jo & 2) != 0;
        float u0 = b1s ? s1 : s0;
        float u1 = b1s ? s3 : s2;
        u0 += __shfl_xor(u0, 4);
        u1 += __shfl_xor(u1, 4);
        float res = ((jo & 4) ? u1 : u0) + hBv[it];
        out[grow * OUTF + jo] = res;    // wave stores 64 consecutive dwords
    }
}

extern "C" void kernel_launch(void* const* d_in, const int* in_sizes, int n_in,
                              void* d_out, int out_size, void* d_ws, size_t ws_size,
                              hipStream_t stream) {
    const float* x    = (const float*)d_in[0];
    const int*   task = (const int*)  d_in[1];
    const float* W0   = (const float*)d_in[2];
    const float* b0   = (const float*)d_in[3];
    const float* W1   = (const float*)d_in[4];
    const float* b1   = (const float*)d_in[5];
    const float* W2   = (const float*)d_in[6];
    const float* b2   = (const float*)d_in[7];
    const float* hW   = (const float*)d_in[8];
    const float* hB   = (const float*)d_in[9];
    float* out = (float*)d_out;
    _Float16* ws = (_Float16*)d_ws;

    prep_kernel<<<64, 256, 0, stream>>>(W0, W1, W2, hW, ws);
    mtn_mfma_kernel<<<BN / ROWS, NTHR, 0, stream>>>(x, task, b0, b1, b2, hB, ws, out);
}

// Round 22
// 39.771 us; speedup vs baseline: 1.5067x; 1.0049x over previous
//
#include <hip/hip_runtime.h>
#include <stdint.h>
#include <stddef.h>

// MultiTaskTrunkNetwork: 3x (Linear+Tanh) [89->64->64->64] + per-task head [64->8]
// Round 22: r21 (weights->LDS, the confirmed L1-line win) at 8-wave granularity.
//   Single variable vs r21: NTHR 256->512. LDS = 28672(W) + 36864(hs) = 65536B
//   exactly -> 2 blocks/CU = 16 waves/CU (vs 12), weight staging amortized over
//   8 waves (instrs/wave halve). Per-wave trunk/head code byte-identical to r21.

typedef _Float16 half8 __attribute__((ext_vector_type(8)));
typedef _Float16 half4 __attribute__((ext_vector_type(4)));
typedef _Float16 half2v __attribute__((ext_vector_type(2)));
typedef float    f32x4 __attribute__((ext_vector_type(4)));

constexpr int BN = 262144, INF = 89, HID = 64, OUTF = 8, NTASK = 50;
constexpr int NTHR = 512;     // 8 waves
constexpr int NW   = 8;       // waves per block
constexpr int ROWS = 256;     // batch rows per block (32 per wave)
constexpr int HP   = 72;      // LDS h pitch in f16 (144 B: 16B-aligned, 2-way banks)
constexpr int WLF  = 14336;   // frag-ordered weights in f16 (28672 B, contiguous)

// d_ws layout (bytes) — fragment-ordered weights (contiguous block of 28672 B)
constexpr int W0F_OFF = 0;        // [3kk][4ft][64lane][8] f16 = 12288 B
constexpr int W1F_OFF = 12288;    // [2kk][4ft][64lane][8] f16 = 8192 B
constexpr int W2F_OFF = 20480;    // [2kk][4ft][64lane][8] f16 = 8192 B
constexpr int HWT_OFF = 28672;    // [50][8][64] f16 (transposed head weights)

__device__ __forceinline__ float fast_tanh(float v) {
    float e = __expf(2.0f * v);
    return 1.0f - 2.0f * __builtin_amdgcn_rcpf(e + 1.0f);
}

__device__ __forceinline__ float dot2acc(half2v a, half2v b, float c) {
#if __has_builtin(__builtin_amdgcn_fdot2)
    return __builtin_amdgcn_fdot2(a, b, c, false);
#else
    return fmaf((float)a[0], (float)b[0], fmaf((float)a[1], (float)b[1], c));
#endif
}

__global__ void prep_kernel(const float* __restrict__ W0, const float* __restrict__ W1,
                            const float* __restrict__ W2, const float* __restrict__ hW,
                            _Float16* __restrict__ ws) {
    const int tid = blockIdx.x * blockDim.x + threadIdx.x;
    const int stride = gridDim.x * blockDim.x;
    _Float16* w0f = ws + W0F_OFF / 2;
    _Float16* w1f = ws + W1F_OFF / 2;
    _Float16* w2f = ws + W2F_OFF / 2;
    _Float16* hwt = ws + HWT_OFF / 2;
    // layer 0: frag (kk,g) covers k0 = kk*32+g*8, EXCEPT (2,3) which covers
    // k=81..88 with j<7 weights zeroed (those k are duplicated in frag (2,2)).
    for (int i = tid; i < 3 * 4 * 64 * 8; i += stride) {
        int j = i & 7, l = (i >> 3) & 63, fk = i >> 9;   // fk = kk*4+ft
        int kk = fk >> 2, ft = fk & 3;
        int n = ft * 16 + (l & 15);
        int g = l >> 4;
        bool tail = (kk == 2 && g == 3);
        int k = (tail ? 81 : kk * 32 + g * 8) + j;       // always <= 88
        float wv = W0[k * HID + n];
        if (tail && j < 7) wv = 0.0f;                    // duplicate k: zero weight
        w0f[i] = (_Float16)wv;
    }
    for (int i = tid; i < 2 * 4 * 64 * 8; i += stride) {
        int j = i & 7, l = (i >> 3) & 63, fk = i >> 9;
        int kk = fk >> 2, ft = fk & 3;
        int n = ft * 16 + (l & 15);
        int k = kk * 32 + (l >> 4) * 8 + j;
        w1f[i] = (_Float16)W1[k * HID + n];
        w2f[i] = (_Float16)W2[k * HID + n];
    }
    for (int i = tid; i < NTASK * OUTF * HID; i += stride) {   // hwT[t][o][k]
        int t = i / (OUTF * HID), rem = i % (OUTF * HID);
        int o = rem / HID, k = rem % HID;
        hwt[i] = (_Float16)hW[(size_t)t * (HID * OUTF) + k * OUTF + o];
    }
}

__global__ __launch_bounds__(NTHR, 4) void mtn_mfma_kernel(
    const float* __restrict__ x,     // [B, 89]
    const int*   __restrict__ task,  // [B]
    const float* __restrict__ b0, const float* __restrict__ b1,
    const float* __restrict__ b2,
    const float* __restrict__ hB,    // [50, 8] fp32
    const _Float16* __restrict__ ws,
    float* __restrict__ out)         // [B, 8]
{
    __shared__ __align__(16) _Float16 wl[WLF];          // 28672 B: W0F|W1F|W2F
    __shared__ __align__(16) _Float16 hs[NW][32][HP];   // 36864 B, wave-private bands

    const int t = threadIdx.x;
    const int w = t >> 6;            // wave 0..7
    const int l = t & 63;
    const int c = l & 15;            // MFMA col (batch) / A row (feat)
    const int g = l >> 4;            // k-group / D row-group
    const int waveRow = blockIdx.x * ROWS + w * 32;   // global row base of this wave

    const _Float16* hwt = ws + HWT_OFF / 2;

    // ---- stage ALL trunk weights to LDS: 1792 float4 = 3*512 + 256, coalesced
    {
        const float4* src = reinterpret_cast<const float4*>(ws);   // frag block @0
        float4* dst = reinterpret_cast<float4*>(wl);
        #pragma unroll
        for (int i = 0; i < 3; ++i) dst[t + i * NTHR] = src[t + i * NTHR];
        if (t < 1792 - 3 * NTHR) dst[t + 3 * NTHR] = src[t + 3 * NTHR];
    }

    // ---- layer-0 B-fragments: direct global->VGPR, branchless (overlapped tail)
    // (issued before the barrier so HBM latency overlaps the weight staging)
    const int k0_2 = (g == 3) ? 81 : 64 + g * 8;     // kk==2 chunk start
    half8 xf[3][2];
    #pragma unroll
    for (int bt = 0; bt < 2; ++bt) {
        const float* xr = x + (size_t)(waveRow + bt * 16 + c) * INF;
        #pragma unroll
        for (int kk = 0; kk < 3; ++kk) {
            const int k0 = (kk == 2) ? k0_2 : kk * 32 + g * 8;
            float v[8];
            __builtin_memcpy(v, xr + k0, 32);        // in-bounds: k0+8 <= 89
            half8 hb;
            #pragma unroll
            for (int i2 = 0; i2 < 8; ++i2) hb[i2] = (_Float16)v[i2];
            xf[kk][bt] = hb;
        }
    }

    // ---- task indices + head biases
    const int jr = l >> 3, jo = l & 7;
    int   tks[4];
    float hBv[4];
    #pragma unroll
    for (int it = 0; it < 4; ++it)
        tks[it] = task[waveRow + it * 8 + jr];
    #pragma unroll
    for (int it = 0; it < 4; ++it)
        hBv[it] = hB[tks[it] * OUTF + jo];

    __syncthreads();   // weights staged; all af reads below hit LDS

    const _Float16* w0l = wl;                 // [3kk][4ft][64][8]
    const _Float16* w1l = wl + W1F_OFF / 2;   // [2kk][4ft][64][8]
    const _Float16* w2l = wl + W2F_OFF / 2;

    f32x4 acc[4][2];   // [feat-tile][batch-tile]

    // ================= layer 0: K=96-equivalent, A frags from LDS =================
    #pragma unroll
    for (int ft = 0; ft < 4; ++ft) {
        f32x4 bv = *(const f32x4*)(b0 + ft * 16 + g * 4);
        acc[ft][0] = bv; acc[ft][1] = bv;
    }
    #pragma unroll
    for (int kk = 0; kk < 3; ++kk)
        #pragma unroll
        for (int ft = 0; ft < 4; ++ft) {
            half8 af = *(const half8*)(w0l + ((kk * 4 + ft) * 64 + l) * 8);  // ds_read_b128
            acc[ft][0] = __builtin_amdgcn_mfma_f32_16x16x32_f16(af, xf[kk][0], acc[ft][0], 0, 0, 0);
            acc[ft][1] = __builtin_amdgcn_mfma_f32_16x16x32_f16(af, xf[kk][1], acc[ft][1], 0, 0, 0);
        }
    #pragma unroll
    for (int ft = 0; ft < 4; ++ft)
        #pragma unroll
        for (int bt = 0; bt < 2; ++bt) {
            half4 hv;
            #pragma unroll
            for (int r = 0; r < 4; ++r) hv[r] = (_Float16)fast_tanh(acc[ft][bt][r]);
            *(half4*)&hs[w][bt * 16 + c][ft * 16 + g * 4] = hv;   // 8B store
        }

    // ================= layers 1,2: K=64, A and B both from LDS =============
    #pragma unroll
    for (int layer = 0; layer < 2; ++layer) {
        const _Float16* WL  = layer ? w2l : w1l;
        const float*    bia = layer ? b2  : b1;
        #pragma unroll
        for (int ft = 0; ft < 4; ++ft) {
            f32x4 bv = *(const f32x4*)(bia + ft * 16 + g * 4);
            acc[ft][0] = bv; acc[ft][1] = bv;
        }
        #pragma unroll
        for (int kk = 0; kk < 2; ++kk) {
            half8 bf[2];
            #pragma unroll
            for (int bt = 0; bt < 2; ++bt)
                bf[bt] = *(const half8*)&hs[w][bt * 16 + c][kk * 32 + g * 8];  // 16B read
            #pragma unroll
            for (int ft = 0; ft < 4; ++ft) {
                half8 af = *(const half8*)(WL + ((kk * 4 + ft) * 64 + l) * 8);
                acc[ft][0] = __builtin_amdgcn_mfma_f32_16x16x32_f16(af, bf[0], acc[ft][0], 0, 0, 0);
                acc[ft][1] = __builtin_amdgcn_mfma_f32_16x16x32_f16(af, bf[1], acc[ft][1], 0, 0, 0);
            }
        }
        #pragma unroll
        for (int ft = 0; ft < 4; ++ft)
            #pragma unroll
            for (int bt = 0; bt < 2; ++bt) {
                half4 hv;
                #pragma unroll
                for (int r = 0; r < 4; ++r) hv[r] = (_Float16)fast_tanh(acc[ft][bt][r]);
                *(half4*)&hs[w][bt * 16 + c][ft * 16 + g * 4] = hv;
            }
    }

    // ================= head: coalesced weight chunks + transpose-reduce =============
    #pragma unroll
    for (int it = 0; it < 4; ++it) {
        const int r = it * 8 + jr;
        const size_t grow = (size_t)waveRow + r;
        const int tk = tks[it];
        const _Float16* wp = hwt + (size_t)tk * (OUTF * HID) + jo * 8;  // chunk jo
        const half8 hv = *(const half8*)&hs[w][r][jo * 8];              // 1 read/it

        float p[8];
        #pragma unroll
        for (int o = 0; o < 8; ++o) {
            half8 wv = *(const half8*)(wp + o * HID);   // 8 lanes -> 128B contiguous
            float a = 0.0f;
            #pragma unroll
            for (int pp = 0; pp < 4; ++pp) {
                half2v av = {hv[2 * pp], hv[2 * pp + 1]};
                half2v bv = {wv[2 * pp], wv[2 * pp + 1]};
                a = dot2acc(av, bv, a);
            }
            p[o] = a;
        }
        // transpose-reduce across the 8 jo-lanes (static indices only)
        float t0 = p[0] + __shfl_xor(p[0], 1);
        float t1 = p[1] + __shfl_xor(p[1], 1);
        float t2 = p[2] + __shfl_xor(p[2], 1);
        float t3 = p[3] + __shfl_xor(p[3], 1);
        float t4 = p[4] + __shfl_xor(p[4], 1);
        float t5 = p[5] + __shfl_xor(p[5], 1);
        float t6 = p[6] + __shfl_xor(p[6], 1);
        float t7 = p[7] + __shfl_xor(p[7], 1);
        const bool b0s = (jo & 1) != 0;
        float s0 = b0s ? t1 : t0;
        float s1 = b0s ? t3 : t2;
        float s2 = b0s ? t5 : t4;
        float s3 = b0s ? t7 : t6;
        s0 += __shfl_xor(s0, 2);
        s1 += __shfl_xor(s1, 2);
        s2 += __shfl_xor(s2, 2);
        s3 += __shfl_xor(s3, 2);
        const bool b1s = (jo & 2) != 0;
        float u0 = b1s ? s1 : s0;
        float u1 = b1s ? s3 : s2;
        u0 += __shfl_xor(u0, 4);
        u1 += __shfl_xor(u1, 4);
        float res = ((jo & 4) ? u1 : u0) + hBv[it];
        out[grow * OUTF + jo] = res;    // wave stores 64 consecutive dwords
    }
}

extern "C" void kernel_launch(void* const* d_in, const int* in_sizes, int n_in,
                              void* d_out, int out_size, void* d_ws, size_t ws_size,
                              hipStream_t stream) {
    const float* x    = (const float*)d_in[0];
    const int*   task = (const int*)  d_in[1];
    const float* W0   = (const float*)d_in[2];
    const float* b0   = (const float*)d_in[3];
    const float* W1   = (const float*)d_in[4];
    const float* b1   = (const float*)d_in[5];
    const float* W2   = (const float*)d_in[6];
    const float* b2   = (const float*)d_in[7];
    const float* hW   = (const float*)d_in[8];
    const float* hB   = (const float*)d_in[9];
    float* out = (float*)d_out;
    _Float16* ws = (_Float16*)d_ws;

    prep_kernel<<<64, 256, 0, stream>>>(W0, W1, W2, hW, ws);
    mtn_mfma_kernel<<<BN / ROWS, NTHR, 0, stream>>>(x, task, b0, b1, b2, hB, ws, out);
}